// Round 13
// baseline (182.353 us; speedup 1.0000x reference)
//
#include <hip/hip_runtime.h>
#include <cstdint>
#include <cstddef>

#define N0C 262144
#define N1C 65536
#define N2C 16384
#define E1C 1048576
#define E2C 262144
#define XN4 (N0C * 128 / 4)
#define XHALF (XN4 / 2)
// packed pair: bits 0..17 = src (N0C=2^18), bits 18..25 = dst-local (<=255)

typedef __attribute__((ext_vector_type(8))) short bf16x8;
typedef __attribute__((ext_vector_type(4))) float f32x4;

__device__ __forceinline__ unsigned short f2bf(float f) {
  union { float f; unsigned u; } q; q.f = f;
  unsigned r = q.u + 0x7fffu + ((q.u >> 16) & 1u);
  return (unsigned short)(r >> 16);
}
__device__ __forceinline__ float blo(unsigned u) {
  union { unsigned u; float f; } q; q.u = u << 16; return q.f;
}
__device__ __forceinline__ float bhi(unsigned u) {
  union { unsigned u; float f; } q; q.u = u & 0xffff0000u; return q.f;
}
__device__ __forceinline__ void gl_lds16(const void* g, void* l) {
  __builtin_amdgcn_global_load_lds((const __attribute__((address_space(1))) void*)g,
                                   (__attribute__((address_space(3))) void*)l, 16, 0, 0);
}

__device__ __forceinline__ void cvt_range(const float4* __restrict__ x,
                                          ushort4* __restrict__ xb,
                                          int i, int stride, int end) {
  for (; i < end; i += stride) {
    float4 v = x[i];
    ushort4 o;
    o.x = f2bf(v.x); o.y = f2bf(v.y); o.z = f2bf(v.z); o.w = f2bf(v.w);
    xb[i] = o;
  }
}

// per-wave layer-1 gather-aggregate for dst row `wid` (lane layout: 4 edges x 16 lanes)
__device__ __forceinline__ void agg1_row(const ushort* __restrict__ xb,
                                         const int* __restrict__ ssrc,
                                         const int* __restrict__ off,
                                         const int* __restrict__ cnt,
                                         ushort* __restrict__ aggr,
                                         int wid, int lane) {
  int grp = lane >> 4;
  int cl = lane & 15;
  int start = __builtin_amdgcn_readfirstlane(off[wid]);
  int n = __builtin_amdgcn_readfirstlane(cnt[wid]);
  float a0 = 0.f, a1 = 0.f, a2 = 0.f, a3 = 0.f, a4 = 0.f, a5 = 0.f, a6 = 0.f, a7 = 0.f;
  int j = 0;
  for (; j + 8 <= n; j += 8) {
    int sa = ssrc[start + j + grp];
    int sb = ssrc[start + j + 4 + grp];
    uint4 va = *(const uint4*)(xb + (size_t)sa * 128 + cl * 8);
    uint4 vb = *(const uint4*)(xb + (size_t)sb * 128 + cl * 8);
    a0 += blo(va.x) + blo(vb.x); a1 += bhi(va.x) + bhi(vb.x);
    a2 += blo(va.y) + blo(vb.y); a3 += bhi(va.y) + bhi(vb.y);
    a4 += blo(va.z) + blo(vb.z); a5 += bhi(va.z) + bhi(vb.z);
    a6 += blo(va.w) + blo(vb.w); a7 += bhi(va.w) + bhi(vb.w);
  }
  if (j + 4 <= n) {
    int s = ssrc[start + j + grp];
    uint4 v = *(const uint4*)(xb + (size_t)s * 128 + cl * 8);
    a0 += blo(v.x); a1 += bhi(v.x); a2 += blo(v.y); a3 += bhi(v.y);
    a4 += blo(v.z); a5 += bhi(v.z); a6 += blo(v.w); a7 += bhi(v.w);
    j += 4;
  }
  if (grp < n - j) {
    int s = ssrc[start + j + grp];
    uint4 v = *(const uint4*)(xb + (size_t)s * 128 + cl * 8);
    a0 += blo(v.x); a1 += bhi(v.x); a2 += blo(v.y); a3 += bhi(v.y);
    a4 += blo(v.z); a5 += bhi(v.z); a6 += blo(v.w); a7 += bhi(v.w);
  }
#define RED1(v) v += __shfl_xor(v, 16); v += __shfl_xor(v, 32);
  RED1(a0) RED1(a1) RED1(a2) RED1(a3) RED1(a4) RED1(a5) RED1(a6) RED1(a7)
#undef RED1
  if (lane < 16) {
    float inv = (n > 0) ? 1.0f / (float)n : 0.f;
    uint4 o;
    o.x = (unsigned)f2bf(a0 * inv) | ((unsigned)f2bf(a1 * inv) << 16);
    o.y = (unsigned)f2bf(a2 * inv) | ((unsigned)f2bf(a3 * inv) << 16);
    o.z = (unsigned)f2bf(a4 * inv) | ((unsigned)f2bf(a5 * inv) << 16);
    o.w = (unsigned)f2bf(a6 * inv) | ((unsigned)f2bf(a7 * inv) << 16);
    *(uint4*)(aggr + (size_t)wid * 128 + cl * 8) = o;
  }
}

// per-block mgemm1 body: 512 threads, 128x256 tile at row base i0
__device__ __forceinline__ void mgemm1_body(
    const ushort* __restrict__ aggr1, const ushort* __restrict__ xb,
    const ushort* __restrict__ W1lb, const ushort* __restrict__ W1rb,
    const float* __restrict__ b1, ushort* __restrict__ h1b,
    ushort* smem, int i0, int t) {
  ushort* sA = smem;
  ushort* sB = smem + 8192;
  int lane = t & 63;
  int w = t >> 6;
  int wm = w >> 2, wn = w & 3;
  int sr = t >> 3;
  int sc = (t & 7) ^ (sr & 7);
  int quad = lane >> 4;
  int l15 = lane & 15;
  int xorv = lane & 7;

  f32x4 acc[4][4];
#pragma unroll
  for (int i = 0; i < 4; ++i)
#pragma unroll
    for (int j = 0; j < 4; ++j) acc[i][j] = (f32x4)(0.f);

  for (int kt = 0; kt < 4; ++kt) {
    const ushort* Asrc = (kt < 2) ? aggr1 : xb;
    const ushort* Bsrc = (kt < 2) ? W1lb : W1rb;
    int koff = (kt & 1) * 64;
#pragma unroll
    for (int it = 0; it < 2; ++it) {
      int r = it * 64 + sr;
      gl_lds16(Asrc + (size_t)(i0 + r) * 128 + koff + sc * 8, sA + (it * 512 + t) * 8);
    }
#pragma unroll
    for (int it = 0; it < 4; ++it) {
      int r = it * 64 + sr;
      gl_lds16(Bsrc + (size_t)r * 128 + koff + sc * 8, sB + (it * 512 + t) * 8);
    }
    __syncthreads();
#pragma unroll
    for (int s = 0; s < 2; ++s) {
      int chunk = ((s * 4 + quad) ^ xorv) * 8;
      bf16x8 av[4], bv[4];
#pragma unroll
      for (int fi = 0; fi < 4; ++fi)
        av[fi] = *(const bf16x8*)(sA + (wm * 64 + fi * 16 + l15) * 64 + chunk);
#pragma unroll
      for (int fj = 0; fj < 4; ++fj)
        bv[fj] = *(const bf16x8*)(sB + (wn * 64 + fj * 16 + l15) * 64 + chunk);
#pragma unroll
      for (int fi = 0; fi < 4; ++fi)
#pragma unroll
        for (int fj = 0; fj < 4; ++fj)
          acc[fi][fj] = __builtin_amdgcn_mfma_f32_16x16x32_bf16(av[fi], bv[fj], acc[fi][fj], 0, 0, 0);
    }
    __syncthreads();
  }

  for (int ph = 0; ph < 2; ++ph) {
    if (wm == ph) {
      ushort* eb = smem + (w & 3) * 4096;
#pragma unroll
      for (int fj = 0; fj < 4; ++fj) {
        float bias = b1[wn * 64 + fj * 16 + l15];
#pragma unroll
        for (int fi = 0; fi < 4; ++fi)
#pragma unroll
          for (int r = 0; r < 4; ++r) {
            float v = fmaxf(acc[fi][fj][r] + bias, 0.f);
            eb[(fi * 16 + quad * 4 + r) * 64 + fj * 16 + l15] = f2bf(v);
          }
      }
#pragma unroll
      for (int i = 0; i < 16; ++i) {
        int row = i * 4 + (lane >> 4);
        uint2 v = *(const uint2*)(eb + row * 64 + l15 * 4);
        *(uint2*)(h1b + (size_t)(i0 + wm * 64 + row) * 256 + wn * 64 + l15 * 4) = v;
      }
    }
    __syncthreads();
  }
}

// ---------------- fused weight cvt + btail zero ----------------
__global__ __launch_bounds__(256) void cvtw_kernel(
    const float4* __restrict__ W1l, const float4* __restrict__ W1r,
    const float4* __restrict__ W2l, const float4* __restrict__ W2r,
    ushort4* __restrict__ W1lb, ushort4* __restrict__ W1rb,
    ushort4* __restrict__ W2lb, ushort4* __restrict__ W2rb,
    int* __restrict__ btail) {
  int y = blockIdx.y;
  int i = blockIdx.x * 256 + threadIdx.x;
  if (y == 4) {
    if (i < 512) btail[i] = 0;
    return;
  }
  const float4* in; ushort4* outp; int n4;
  if (y == 0)      { in = W1l; outp = W1lb; n4 = 8192; }
  else if (y == 1) { in = W1r; outp = W1rb; n4 = 8192; }
  else if (y == 2) { in = W2l; outp = W2lb; n4 = 4096; }
  else             { in = W2r; outp = W2rb; n4 = 4096; }
  if (i < n4) {
    float4 v = in[i];
    ushort4 o;
    o.x = f2bf(v.x); o.y = f2bf(v.y); o.z = f2bf(v.z); o.w = f2bf(v.w);
    outp[i] = o;
  }
}

// ---------------- mega: binA (0..319) + cvtx first half ----------------
__global__ __launch_bounds__(256) void mega_kernel(
    const int* __restrict__ src1, const int* __restrict__ dst1,
    const int* __restrict__ src2, const int* __restrict__ dst2,
    int* __restrict__ btail, unsigned* __restrict__ pair1, unsigned* __restrict__ pair2,
    const float4* __restrict__ x, ushort4* __restrict__ xb) {
  __shared__ int hist[256];
  __shared__ int lofs[256];
  __shared__ int gbase[256];
  __shared__ unsigned stg[4096];
  __shared__ unsigned char bstg[4096];
  int b = blockIdx.x;
  int t = threadIdx.x;
  if (b >= 320) {
    cvt_range(x, xb, (b - 320) * 256 + t, 2048 * 256, XHALF);
    return;
  }
  const int* src; const int* dst; int shift; int dmask; int* bt; unsigned* pb; int e0;
  if (b < 256) { src = src1; dst = dst1; shift = 8; dmask = 255; bt = btail;       pb = pair1; e0 = b * 4096; }
  else         { src = src2; dst = dst2; shift = 6; dmask = 63;  bt = btail + 256; pb = pair2; e0 = (b - 256) * 4096; }
  hist[t] = 0;
  __syncthreads();
  unsigned pk[16]; int bk[16], rk[16];
#pragma unroll
  for (int k = 0; k < 16; ++k) {
    int e = e0 + k * 256 + t;
    int s = src[e];
    int d = dst[e];
    bk[k] = d >> shift;
    pk[k] = ((unsigned)(d & dmask) << 18) | (unsigned)s;
    rk[k] = atomicAdd(&hist[bk[k]], 1);
  }
  __syncthreads();
  int v = hist[t];
  lofs[t] = v;
  __syncthreads();
  for (int ofs = 1; ofs < 256; ofs <<= 1) {
    int add = (t >= ofs) ? lofs[t - ofs] : 0;
    __syncthreads();
    lofs[t] += add;
    __syncthreads();
  }
  gbase[t] = atomicAdd(&bt[t], v);
  int excl = lofs[t] - v;
  lofs[t] = excl;
  __syncthreads();
#pragma unroll
  for (int k = 0; k < 16; ++k) {
    int p = lofs[bk[k]] + rk[k];
    stg[p] = pk[k];
    bstg[p] = (unsigned char)bk[k];
  }
  __syncthreads();
  for (int i = t; i < 4096; i += 256) {
    int bki = bstg[i];
    int idx = gbase[bki] + (i - lofs[bki]);
    if (idx < 8192)
      pb[(size_t)bki * 8192 + idx] = stg[i];
  }
}

// binB: one block per bucket (0..511) + cvtx second half (512..2559)
__global__ __launch_bounds__(256) void binB_kernel(
    const unsigned* __restrict__ pair1, const unsigned* __restrict__ pair2,
    const int* __restrict__ btail,
    int* __restrict__ off1, int* __restrict__ cnt1, int* __restrict__ ssrc1,
    int* __restrict__ off2, int* __restrict__ cnt2, int* __restrict__ ssrc2,
    const float4* __restrict__ x, ushort4* __restrict__ xb) {
  __shared__ int lcnt[256];
  __shared__ int loff[256];
  __shared__ int lcnt2[256];
  __shared__ unsigned stage[8192];
  int b = blockIdx.x;
  int t = threadIdx.x;
  if (b >= 512) {
    cvt_range(x, xb, XHALF + (b - 512) * 256 + t, 2048 * 256, XN4);
    return;
  }
  const unsigned* pb; const int* bt; int dpb; int* off; int* cnt; int* ssrc; int bl;
  if (b < 256) { bl = b;       pb = pair1 + (size_t)bl * 8192; bt = btail;       dpb = 256; off = off1; cnt = cnt1; ssrc = ssrc1; }
  else         { bl = b - 256; pb = pair2 + (size_t)bl * 8192; bt = btail + 256; dpb = 64;  off = off2; cnt = cnt2; ssrc = ssrc2; }
  lcnt[t] = (t < bl) ? bt[t] : 0;
  __syncthreads();
  for (int ofs = 128; ofs > 0; ofs >>= 1) {
    if (t < ofs) lcnt[t] += lcnt[t + ofs];
    __syncthreads();
  }
  int base = lcnt[0];
  __syncthreads();
  lcnt[t] = 0;
  lcnt2[t] = 0;
  __syncthreads();
  int n = bt[bl];
  if (n > 8192) n = 8192;
  for (int i = t; i < n; i += 256) {
    unsigned p = pb[i];
    atomicAdd(&lcnt[p >> 18], 1);
  }
  __syncthreads();
  int v = lcnt[t];
  loff[t] = v;
  __syncthreads();
  for (int ofs = 1; ofs < 256; ofs <<= 1) {
    int add = (t >= ofs) ? loff[t - ofs] : 0;
    __syncthreads();
    loff[t] += add;
    __syncthreads();
  }
  int excl = loff[t] - v;
  loff[t] = excl;
  if (t < dpb) {
    cnt[bl * dpb + t] = v;
    off[bl * dpb + t] = base + excl;
  }
  __syncthreads();
  for (int i = t; i < n; i += 256) {
    unsigned p = pb[i];
    int dl = p >> 18;
    int r = atomicAdd(&lcnt2[dl], 1);
    stage[loff[dl] + r] = p & 0x3FFFFu;
  }
  __syncthreads();
  for (int i = t; i < n; i += 256) ssrc[base + i] = (int)stage[i];
}

// ---------------- layer-1 agg, standalone (rows rbase..rbase+4*grid) ----------------
__global__ __launch_bounds__(256) void agg1_kernel(const ushort* __restrict__ xb,
                                                   const int* __restrict__ ssrc,
                                                   const int* __restrict__ off,
                                                   const int* __restrict__ cnt,
                                                   ushort* __restrict__ aggr,
                                                   int rbase) {
  int wid = rbase + ((blockIdx.x * 256 + threadIdx.x) >> 6);
  agg1_row(xb, ssrc, off, cnt, aggr, wid, threadIdx.x & 63);
}

// ---------------- pipelined: blocks 0..255 GEMM rows 0..32767; 256.. agg rows 32768.. ----
__global__ __launch_bounds__(512) void mm1agg_kernel(
    const ushort* __restrict__ aggr1, const ushort* __restrict__ xb,
    const ushort* __restrict__ W1lb, const ushort* __restrict__ W1rb,
    const float* __restrict__ b1, ushort* __restrict__ h1b,
    const int* __restrict__ ssrc, const int* __restrict__ off,
    const int* __restrict__ cnt, ushort* __restrict__ aggr_out) {
  __shared__ ushort smem[24576];
  int b = blockIdx.x;
  int t = threadIdx.x;
  if (b < 256) {
    mgemm1_body(aggr1, xb, W1lb, W1rb, b1, h1b, smem, b * 128, t);
  } else {
    int wid = 32768 + (b - 256) * 8 + (t >> 6);
    agg1_row(xb, ssrc, off, cnt, aggr_out, wid, t & 63);
  }
}

// ---------------- mgemm1 standalone (rows rbase..) ----------------
__global__ __launch_bounds__(512) void mgemm1_kernel(
    const ushort* __restrict__ aggr1, const ushort* __restrict__ xb,
    const ushort* __restrict__ W1lb, const ushort* __restrict__ W1rb,
    const float* __restrict__ b1, ushort* __restrict__ h1b, int rbase) {
  __shared__ ushort smem[24576];
  mgemm1_body(aggr1, xb, W1lb, W1rb, b1, h1b, smem, rbase + blockIdx.x * 128, threadIdx.x);
}

// ---------------- layer-2 aggregation ----------------
__global__ __launch_bounds__(256) void agg2_kernel(const ushort* __restrict__ h1b,
                                                   const int* __restrict__ ssrc,
                                                   const int* __restrict__ off,
                                                   const int* __restrict__ cnt,
                                                   ushort* __restrict__ aggr) {
  int wid = (blockIdx.x * 256 + threadIdx.x) >> 6;
  int lane = threadIdx.x & 63;
  int grp = lane >> 5;
  int cl = lane & 31;
  int start = __builtin_amdgcn_readfirstlane(off[wid]);
  int n = __builtin_amdgcn_readfirstlane(cnt[wid]);
  float a0 = 0.f, a1 = 0.f, a2 = 0.f, a3 = 0.f, a4 = 0.f, a5 = 0.f, a6 = 0.f, a7 = 0.f;
  int j = 0;
  for (; j + 8 <= n; j += 8) {
    int s0 = ssrc[start + j + grp];
    int s1 = ssrc[start + j + 2 + grp];
    int s2 = ssrc[start + j + 4 + grp];
    int s3 = ssrc[start + j + 6 + grp];
    uint4 v0 = *(const uint4*)(h1b + (size_t)s0 * 256 + cl * 8);
    uint4 v1 = *(const uint4*)(h1b + (size_t)s1 * 256 + cl * 8);
    uint4 v2 = *(const uint4*)(h1b + (size_t)s2 * 256 + cl * 8);
    uint4 v3 = *(const uint4*)(h1b + (size_t)s3 * 256 + cl * 8);
    a0 += blo(v0.x) + blo(v1.x) + blo(v2.x) + blo(v3.x);
    a1 += bhi(v0.x) + bhi(v1.x) + bhi(v2.x) + bhi(v3.x);
    a2 += blo(v0.y) + blo(v1.y) + blo(v2.y) + blo(v3.y);
    a3 += bhi(v0.y) + bhi(v1.y) + bhi(v2.y) + bhi(v3.y);
    a4 += blo(v0.z) + blo(v1.z) + blo(v2.z) + blo(v3.z);
    a5 += bhi(v0.z) + bhi(v1.z) + bhi(v2.z) + bhi(v3.z);
    a6 += blo(v0.w) + blo(v1.w) + blo(v2.w) + blo(v3.w);
    a7 += bhi(v0.w) + bhi(v1.w) + bhi(v2.w) + bhi(v3.w);
  }
  for (; j + 2 <= n; j += 2) {
    int s = ssrc[start + j + grp];
    uint4 v = *(const uint4*)(h1b + (size_t)s * 256 + cl * 8);
    a0 += blo(v.x); a1 += bhi(v.x); a2 += blo(v.y); a3 += bhi(v.y);
    a4 += blo(v.z); a5 += bhi(v.z); a6 += blo(v.w); a7 += bhi(v.w);
  }
  if (grp < n - j) {
    int s = ssrc[start + j + grp];
    uint4 v = *(const uint4*)(h1b + (size_t)s * 256 + cl * 8);
    a0 += blo(v.x); a1 += bhi(v.x); a2 += blo(v.y); a3 += bhi(v.y);
    a4 += blo(v.z); a5 += bhi(v.z); a6 += blo(v.w); a7 += bhi(v.w);
  }
#define RED2(v) v += __shfl_xor(v, 32);
  RED2(a0) RED2(a1) RED2(a2) RED2(a3) RED2(a4) RED2(a5) RED2(a6) RED2(a7)
#undef RED2
  if (lane < 32) {
    float inv = (n > 0) ? 1.0f / (float)n : 0.f;
    uint4 o;
    o.x = (unsigned)f2bf(a0 * inv) | ((unsigned)f2bf(a1 * inv) << 16);
    o.y = (unsigned)f2bf(a2 * inv) | ((unsigned)f2bf(a3 * inv) << 16);
    o.z = (unsigned)f2bf(a4 * inv) | ((unsigned)f2bf(a5 * inv) << 16);
    o.w = (unsigned)f2bf(a6 * inv) | ((unsigned)f2bf(a7 * inv) << 16);
    *(uint4*)(aggr + (size_t)wid * 256 + cl * 8) = o;
  }
}

// ---------------- MFMA GEMM2 + bias + log_softmax ----------------
__global__ __launch_bounds__(256) void mgemm2_kernel(
    const ushort* __restrict__ aggr2, const ushort* __restrict__ h1b,
    const ushort* __restrict__ W2lb, const ushort* __restrict__ W2rb,
    const float* __restrict__ b2, float* __restrict__ out) {
  __shared__ ushort sA[64 * 64];
  __shared__ ushort sB[64 * 64];
  int t = threadIdx.x;
  int lane = t & 63;
  int w = t >> 6;
  int i0 = blockIdx.x * 64;

  int sr = t >> 3;
  int sc = (t & 7) ^ (sr & 7);
  int quad = lane >> 4;
  int l15 = lane & 15;
  int xorv = lane & 7;

  f32x4 acc[4];
#pragma unroll
  for (int j = 0; j < 4; ++j) acc[j] = (f32x4)(0.f);

  for (int kt = 0; kt < 8; ++kt) {
    const ushort* Asrc = (kt < 4) ? aggr2 : h1b;
    const ushort* Bsrc = (kt < 4) ? W2lb : W2rb;
    int koff = (kt & 3) * 64;
#pragma unroll
    for (int it = 0; it < 2; ++it) {
      int r = it * 32 + sr;
      gl_lds16(Asrc + (size_t)(i0 + r) * 256 + koff + sc * 8, sA + (it * 256 + t) * 8);
    }
#pragma unroll
    for (int it = 0; it < 2; ++it) {
      int r = it * 32 + sr;
      gl_lds16(Bsrc + (size_t)r * 256 + koff + sc * 8, sB + (it * 256 + t) * 8);
    }
    __syncthreads();
#pragma unroll
    for (int s = 0; s < 2; ++s) {
      int chunk = ((s * 4 + quad) ^ xorv) * 8;
      bf16x8 av = *(const bf16x8*)(sA + (w * 16 + l15) * 64 + chunk);
      bf16x8 bv[4];
#pragma unroll
      for (int fj = 0; fj < 4; ++fj)
        bv[fj] = *(const bf16x8*)(sB + (fj * 16 + l15) * 64 + chunk);
#pragma unroll
      for (int fj = 0; fj < 4; ++fj)
        acc[fj] = __builtin_amdgcn_mfma_f32_16x16x32_bf16(av, bv[fj], acc[fj], 0, 0, 0);
    }
    __syncthreads();
  }

  float b2c[4];
#pragma unroll
  for (int fj = 0; fj < 4; ++fj) b2c[fj] = b2[fj * 16 + l15];

#pragma unroll
  for (int r = 0; r < 4; ++r) {
    int row = i0 + w * 16 + quad * 4 + r;
    float v[4];
#pragma unroll
    for (int fj = 0; fj < 4; ++fj) v[fj] = acc[fj][r] + b2c[fj];
    float m = fmaxf(fmaxf(v[0], v[1]), fmaxf(v[2], v[3]));
    m = fmaxf(m, __shfl_xor(m, 1));
    m = fmaxf(m, __shfl_xor(m, 2));
    m = fmaxf(m, __shfl_xor(m, 4));
    m = fmaxf(m, __shfl_xor(m, 8));
    float ssum = __expf(v[0] - m) + __expf(v[1] - m) + __expf(v[2] - m) + __expf(v[3] - m);
    ssum += __shfl_xor(ssum, 1);
    ssum += __shfl_xor(ssum, 2);
    ssum += __shfl_xor(ssum, 4);
    ssum += __shfl_xor(ssum, 8);
    float lg = m + __logf(ssum);
#pragma unroll
    for (int fj = 0; fj < 4; ++fj)
      out[(size_t)row * 64 + fj * 16 + l15] = v[fj] - lg;
  }
}

// ---------------- launch ----------------

extern "C" void kernel_launch(void* const* d_in, const int* in_sizes, int n_in,
                              void* d_out, int out_size, void* d_ws, size_t ws_size,
                              hipStream_t stream) {
  const float* x   = (const float*)d_in[0];
  const int* src1  = (const int*)d_in[1];
  const int* dst1  = (const int*)d_in[2];
  const int* src2  = (const int*)d_in[3];
  const int* dst2  = (const int*)d_in[4];
  const float* W1l = (const float*)d_in[5];
  const float* W1r = (const float*)d_in[6];
  const float* b1  = (const float*)d_in[7];
  const float* W2l = (const float*)d_in[8];
  const float* W2r = (const float*)d_in[9];
  const float* b2  = (const float*)d_in[10];
  float* out = (float*)d_out;

  char* base = (char*)d_ws;
  ushort* xb   = (ushort*)base;                          // 67.1 MB
  ushort* ag1b = (ushort*)(base + 67108864);             // 16.8 MB
  ushort* ag2b = (ushort*)(base + 83886080);             // 8.4 MB
  unsigned* pair1 = (unsigned*)(base + 92274688);        // 8.4 MB
  unsigned* pair2 = (unsigned*)(base + 100663296);       // 8.4 MB
  ushort* h1b  = (ushort*)(base + 109051904);            // 33.6 MB
  int* cnt1  = (int*)(base + 142606336);                 // N1
  int* off1  = cnt1 + N1C;                               // N1
  int* cnt2  = off1 + N1C;                               // N2
  int* off2  = cnt2 + N2C;                               // N2
  int* btail = off2 + N2C;                               // 512
  int* ssrc1 = btail + 512;                              // E1
  int* ssrc2 = ssrc1 + E1C;                              // E2
  ushort* W1lb = (ushort*)(ssrc2 + E2C);                 // 32768
  ushort* W1rb = W1lb + 32768;
  ushort* W2lb = W1rb + 32768;
  ushort* W2rb = W2lb + 16384;

  // weights -> bf16 + btail zero (must precede mega's binA atomics)
  cvtw_kernel<<<dim3(32, 5), 256, 0, stream>>>(
      (const float4*)W1l, (const float4*)W1r, (const float4*)W2l, (const float4*)W2r,
      (ushort4*)W1lb, (ushort4*)W1rb, (ushort4*)W2lb, (ushort4*)W2rb, btail);

  // binA + cvtx first half
  mega_kernel<<<2368, 256, 0, stream>>>(src1, dst1, src2, dst2, btail, pair1, pair2,
                                        (const float4*)x, (ushort4*)xb);

  // bucket sort + cvtx second half
  binB_kernel<<<2560, 256, 0, stream>>>(pair1, pair2, btail,
                                        off1, cnt1, ssrc1, off2, cnt2, ssrc2,
                                        (const float4*)x, (ushort4*)xb);

  // layer 1, pipelined in halves:
  // (1) aggregate rows 0..32767
  agg1_kernel<<<8192, 256, 0, stream>>>(xb, ssrc1, off1, cnt1, ag1b, 0);
  // (2) GEMM rows 0..32767 || aggregate rows 32768..65535
  mm1agg_kernel<<<4352, 512, 0, stream>>>(ag1b, xb, W1lb, W1rb, b1, h1b,
                                          ssrc1, off1, cnt1, ag1b);
  // (3) GEMM rows 32768..65535
  mgemm1_kernel<<<256, 512, 0, stream>>>(ag1b, xb, W1lb, W1rb, b1, h1b, 32768);

  // layer 2
  agg2_kernel<<<N2C / 4, 256, 0, stream>>>(h1b, ssrc2, off2, cnt2, ag2b);
  mgemm2_kernel<<<N2C / 64, 256, 0, stream>>>(ag2b, h1b, W2lb, W2rb, b2, out);
}

// Round 14
// 155.255 us; speedup vs baseline: 1.1745x; 1.1745x over previous
//
#include <hip/hip_runtime.h>
#include <cstdint>
#include <cstddef>

#define N0C 262144
#define N1C 65536
#define N2C 16384
#define E1C 1048576
#define E2C 262144
#define XN4 (N0C * 128 / 4)   // float4 count of x
#define XHALF (XN4 / 2)
// IN_C=128, HID_C=256, OUT_C=64
// packed pair: bits 0..17 = src (N0C=2^18), bits 18..25 = dst-local (<=255)

typedef __attribute__((ext_vector_type(8))) short bf16x8;
typedef __attribute__((ext_vector_type(4))) float f32x4;

__device__ __forceinline__ unsigned short f2bf(float f) {
  union { float f; unsigned u; } q; q.f = f;
  unsigned r = q.u + 0x7fffu + ((q.u >> 16) & 1u);
  return (unsigned short)(r >> 16);
}
__device__ __forceinline__ float blo(unsigned u) {
  union { unsigned u; float f; } q; q.u = u << 16; return q.f;
}
__device__ __forceinline__ float bhi(unsigned u) {
  union { unsigned u; float f; } q; q.u = u & 0xffff0000u; return q.f;
}
__device__ __forceinline__ void gl_lds16(const void* g, void* l) {
  __builtin_amdgcn_global_load_lds((const __attribute__((address_space(1))) void*)g,
                                   (__attribute__((address_space(3))) void*)l, 16, 0, 0);
}

__device__ __forceinline__ void cvt_range(const float4* __restrict__ x,
                                          ushort4* __restrict__ xb,
                                          int i, int stride, int end) {
  for (; i < end; i += stride) {
    float4 v = x[i];
    ushort4 o;
    o.x = f2bf(v.x); o.y = f2bf(v.y); o.z = f2bf(v.z); o.w = f2bf(v.w);
    xb[i] = o;
  }
}

// ---------------- fused weight cvt + btail zero ----------------
__global__ __launch_bounds__(256) void cvtw_kernel(
    const float4* __restrict__ W1l, const float4* __restrict__ W1r,
    const float4* __restrict__ W2l, const float4* __restrict__ W2r,
    ushort4* __restrict__ W1lb, ushort4* __restrict__ W1rb,
    ushort4* __restrict__ W2lb, ushort4* __restrict__ W2rb,
    int* __restrict__ btail) {
  int y = blockIdx.y;
  int i = blockIdx.x * 256 + threadIdx.x;
  if (y == 4) {
    if (i < 512) btail[i] = 0;
    return;
  }
  const float4* in; ushort4* outp; int n4;
  if (y == 0)      { in = W1l; outp = W1lb; n4 = 8192; }
  else if (y == 1) { in = W1r; outp = W1rb; n4 = 8192; }
  else if (y == 2) { in = W2l; outp = W2lb; n4 = 4096; }
  else             { in = W2r; outp = W2rb; n4 = 4096; }
  if (i < n4) {
    float4 v = in[i];
    ushort4 o;
    o.x = f2bf(v.x); o.y = f2bf(v.y); o.z = f2bf(v.z); o.w = f2bf(v.w);
    outp[i] = o;
  }
}

// ---------------- mega: binA (blocks 0..319) + cvtx first half (blocks 320..2367) ----
__global__ __launch_bounds__(256) void mega_kernel(
    const int* __restrict__ src1, const int* __restrict__ dst1,
    const int* __restrict__ src2, const int* __restrict__ dst2,
    int* __restrict__ btail, unsigned* __restrict__ pair1, unsigned* __restrict__ pair2,
    const float4* __restrict__ x, ushort4* __restrict__ xb) {
  __shared__ int hist[256];
  __shared__ int lofs[256];
  __shared__ int gbase[256];
  __shared__ unsigned stg[4096];
  __shared__ unsigned char bstg[4096];
  int b = blockIdx.x;
  int t = threadIdx.x;
  if (b >= 320) {
    cvt_range(x, xb, (b - 320) * 256 + t, 2048 * 256, XHALF);
    return;
  }
  const int* src; const int* dst; int shift; int dmask; int* bt; unsigned* pb; int e0;
  if (b < 256) { src = src1; dst = dst1; shift = 8; dmask = 255; bt = btail;       pb = pair1; e0 = b * 4096; }
  else         { src = src2; dst = dst2; shift = 6; dmask = 63;  bt = btail + 256; pb = pair2; e0 = (b - 256) * 4096; }
  hist[t] = 0;
  __syncthreads();
  unsigned pk[16]; int bk[16], rk[16];
#pragma unroll
  for (int k = 0; k < 16; ++k) {
    int e = e0 + k * 256 + t;
    int s = src[e];
    int d = dst[e];
    bk[k] = d >> shift;
    pk[k] = ((unsigned)(d & dmask) << 18) | (unsigned)s;
    rk[k] = atomicAdd(&hist[bk[k]], 1);
  }
  __syncthreads();
  int v = hist[t];
  lofs[t] = v;
  __syncthreads();
  for (int ofs = 1; ofs < 256; ofs <<= 1) {
    int add = (t >= ofs) ? lofs[t - ofs] : 0;
    __syncthreads();
    lofs[t] += add;
    __syncthreads();
  }
  gbase[t] = atomicAdd(&bt[t], v);
  int excl = lofs[t] - v;
  lofs[t] = excl;
  __syncthreads();
#pragma unroll
  for (int k = 0; k < 16; ++k) {
    int p = lofs[bk[k]] + rk[k];
    stg[p] = pk[k];
    bstg[p] = (unsigned char)bk[k];
  }
  __syncthreads();
  for (int i = t; i < 4096; i += 256) {
    int bki = bstg[i];
    int idx = gbase[bki] + (i - lofs[bki]);
    if (idx < 8192)
      pb[(size_t)bki * 8192 + idx] = stg[i];
  }
}

// binB: one block per BUCKET (layer1: 0..255, layer2: 256..511), packed uint pairs.
// blocks 512..2559: cvtx second half (overlaps with the bucket sort).
__global__ __launch_bounds__(256) void binB_kernel(
    const unsigned* __restrict__ pair1, const unsigned* __restrict__ pair2,
    const int* __restrict__ btail,
    int* __restrict__ off1, int* __restrict__ cnt1, int* __restrict__ ssrc1,
    int* __restrict__ off2, int* __restrict__ cnt2, int* __restrict__ ssrc2,
    const float4* __restrict__ x, ushort4* __restrict__ xb) {
  __shared__ int lcnt[256];
  __shared__ int loff[256];
  __shared__ int lcnt2[256];
  __shared__ unsigned stage[8192];
  int b = blockIdx.x;
  int t = threadIdx.x;
  if (b >= 512) {
    cvt_range(x, xb, XHALF + (b - 512) * 256 + t, 2048 * 256, XN4);
    return;
  }
  const unsigned* pb; const int* bt; int dpb; int* off; int* cnt; int* ssrc; int bl;
  if (b < 256) { bl = b;       pb = pair1 + (size_t)bl * 8192; bt = btail;       dpb = 256; off = off1; cnt = cnt1; ssrc = ssrc1; }
  else         { bl = b - 256; pb = pair2 + (size_t)bl * 8192; bt = btail + 256; dpb = 64;  off = off2; cnt = cnt2; ssrc = ssrc2; }
  lcnt[t] = (t < bl) ? bt[t] : 0;
  __syncthreads();
  for (int ofs = 128; ofs > 0; ofs >>= 1) {
    if (t < ofs) lcnt[t] += lcnt[t + ofs];
    __syncthreads();
  }
  int base = lcnt[0];
  __syncthreads();
  lcnt[t] = 0;
  lcnt2[t] = 0;
  __syncthreads();
  int n = bt[bl];
  if (n > 8192) n = 8192;
  for (int i = t; i < n; i += 256) {
    unsigned p = pb[i];
    atomicAdd(&lcnt[p >> 18], 1);
  }
  __syncthreads();
  int v = lcnt[t];
  loff[t] = v;
  __syncthreads();
  for (int ofs = 1; ofs < 256; ofs <<= 1) {
    int add = (t >= ofs) ? loff[t - ofs] : 0;
    __syncthreads();
    loff[t] += add;
    __syncthreads();
  }
  int excl = loff[t] - v;
  loff[t] = excl;
  if (t < dpb) {
    cnt[bl * dpb + t] = v;
    off[bl * dpb + t] = base + excl;
  }
  __syncthreads();
  for (int i = t; i < n; i += 256) {
    unsigned p = pb[i];
    int dl = p >> 18;
    int r = atomicAdd(&lcnt2[dl], 1);
    stage[loff[dl] + r] = p & 0x3FFFFu;
  }
  __syncthreads();
  for (int i = t; i < n; i += 256) ssrc[base + i] = (int)stage[i];
}

// ---------------- layer-1 aggregation: bf16 gather, 8 edges in flight ----------------
__global__ __launch_bounds__(256) void agg1_kernel(const ushort* __restrict__ xb,
                                                   const int* __restrict__ ssrc,
                                                   const int* __restrict__ off,
                                                   const int* __restrict__ cnt,
                                                   ushort* __restrict__ aggr) {
  int wid = (blockIdx.x * 256 + threadIdx.x) >> 6;
  int lane = threadIdx.x & 63;
  int grp = lane >> 4;
  int cl = lane & 15;
  int start = __builtin_amdgcn_readfirstlane(off[wid]);
  int n = __builtin_amdgcn_readfirstlane(cnt[wid]);
  float a0 = 0.f, a1 = 0.f, a2 = 0.f, a3 = 0.f, a4 = 0.f, a5 = 0.f, a6 = 0.f, a7 = 0.f;
  int j = 0;
  for (; j + 8 <= n; j += 8) {
    int sa = ssrc[start + j + grp];
    int sb = ssrc[start + j + 4 + grp];
    uint4 va = *(const uint4*)(xb + (size_t)sa * 128 + cl * 8);
    uint4 vb = *(const uint4*)(xb + (size_t)sb * 128 + cl * 8);
    a0 += blo(va.x) + blo(vb.x); a1 += bhi(va.x) + bhi(vb.x);
    a2 += blo(va.y) + blo(vb.y); a3 += bhi(va.y) + bhi(vb.y);
    a4 += blo(va.z) + blo(vb.z); a5 += bhi(va.z) + bhi(vb.z);
    a6 += blo(va.w) + blo(vb.w); a7 += bhi(va.w) + bhi(vb.w);
  }
  if (j + 4 <= n) {
    int s = ssrc[start + j + grp];
    uint4 v = *(const uint4*)(xb + (size_t)s * 128 + cl * 8);
    a0 += blo(v.x); a1 += bhi(v.x); a2 += blo(v.y); a3 += bhi(v.y);
    a4 += blo(v.z); a5 += bhi(v.z); a6 += blo(v.w); a7 += bhi(v.w);
    j += 4;
  }
  if (grp < n - j) {
    int s = ssrc[start + j + grp];
    uint4 v = *(const uint4*)(xb + (size_t)s * 128 + cl * 8);
    a0 += blo(v.x); a1 += bhi(v.x); a2 += blo(v.y); a3 += bhi(v.y);
    a4 += blo(v.z); a5 += bhi(v.z); a6 += blo(v.w); a7 += bhi(v.w);
  }
#define RED1(v) v += __shfl_xor(v, 16); v += __shfl_xor(v, 32);
  RED1(a0) RED1(a1) RED1(a2) RED1(a3) RED1(a4) RED1(a5) RED1(a6) RED1(a7)
#undef RED1
  if (lane < 16) {
    float inv = (n > 0) ? 1.0f / (float)n : 0.f;
    uint4 o;
    o.x = (unsigned)f2bf(a0 * inv) | ((unsigned)f2bf(a1 * inv) << 16);
    o.y = (unsigned)f2bf(a2 * inv) | ((unsigned)f2bf(a3 * inv) << 16);
    o.z = (unsigned)f2bf(a4 * inv) | ((unsigned)f2bf(a5 * inv) << 16);
    o.w = (unsigned)f2bf(a6 * inv) | ((unsigned)f2bf(a7 * inv) << 16);
    *(uint4*)(aggr + (size_t)wid * 128 + cl * 8) = o;
  }
}

// ---------------- layer-2 aggregation: bf16 gather from h1b, 8 edges in flight -------
__global__ __launch_bounds__(256) void agg2_kernel(const ushort* __restrict__ h1b,
                                                   const int* __restrict__ ssrc,
                                                   const int* __restrict__ off,
                                                   const int* __restrict__ cnt,
                                                   ushort* __restrict__ aggr) {
  int wid = (blockIdx.x * 256 + threadIdx.x) >> 6;
  int lane = threadIdx.x & 63;
  int grp = lane >> 5;
  int cl = lane & 31;
  int start = __builtin_amdgcn_readfirstlane(off[wid]);
  int n = __builtin_amdgcn_readfirstlane(cnt[wid]);
  float a0 = 0.f, a1 = 0.f, a2 = 0.f, a3 = 0.f, a4 = 0.f, a5 = 0.f, a6 = 0.f, a7 = 0.f;
  int j = 0;
  for (; j + 8 <= n; j += 8) {
    int s0 = ssrc[start + j + grp];
    int s1 = ssrc[start + j + 2 + grp];
    int s2 = ssrc[start + j + 4 + grp];
    int s3 = ssrc[start + j + 6 + grp];
    uint4 v0 = *(const uint4*)(h1b + (size_t)s0 * 256 + cl * 8);
    uint4 v1 = *(const uint4*)(h1b + (size_t)s1 * 256 + cl * 8);
    uint4 v2 = *(const uint4*)(h1b + (size_t)s2 * 256 + cl * 8);
    uint4 v3 = *(const uint4*)(h1b + (size_t)s3 * 256 + cl * 8);
    a0 += blo(v0.x) + blo(v1.x) + blo(v2.x) + blo(v3.x);
    a1 += bhi(v0.x) + bhi(v1.x) + bhi(v2.x) + bhi(v3.x);
    a2 += blo(v0.y) + blo(v1.y) + blo(v2.y) + blo(v3.y);
    a3 += bhi(v0.y) + bhi(v1.y) + bhi(v2.y) + bhi(v3.y);
    a4 += blo(v0.z) + blo(v1.z) + blo(v2.z) + blo(v3.z);
    a5 += bhi(v0.z) + bhi(v1.z) + bhi(v2.z) + bhi(v3.z);
    a6 += blo(v0.w) + blo(v1.w) + blo(v2.w) + blo(v3.w);
    a7 += bhi(v0.w) + bhi(v1.w) + bhi(v2.w) + bhi(v3.w);
  }
  for (; j + 2 <= n; j += 2) {
    int s = ssrc[start + j + grp];
    uint4 v = *(const uint4*)(h1b + (size_t)s * 256 + cl * 8);
    a0 += blo(v.x); a1 += bhi(v.x); a2 += blo(v.y); a3 += bhi(v.y);
    a4 += blo(v.z); a5 += bhi(v.z); a6 += blo(v.w); a7 += bhi(v.w);
  }
  if (grp < n - j) {
    int s = ssrc[start + j + grp];
    uint4 v = *(const uint4*)(h1b + (size_t)s * 256 + cl * 8);
    a0 += blo(v.x); a1 += bhi(v.x); a2 += blo(v.y); a3 += bhi(v.y);
    a4 += blo(v.z); a5 += bhi(v.z); a6 += blo(v.w); a7 += bhi(v.w);
  }
#define RED2(v) v += __shfl_xor(v, 32);
  RED2(a0) RED2(a1) RED2(a2) RED2(a3) RED2(a4) RED2(a5) RED2(a6) RED2(a7)
#undef RED2
  if (lane < 32) {
    float inv = (n > 0) ? 1.0f / (float)n : 0.f;
    uint4 o;
    o.x = (unsigned)f2bf(a0 * inv) | ((unsigned)f2bf(a1 * inv) << 16);
    o.y = (unsigned)f2bf(a2 * inv) | ((unsigned)f2bf(a3 * inv) << 16);
    o.z = (unsigned)f2bf(a4 * inv) | ((unsigned)f2bf(a5 * inv) << 16);
    o.w = (unsigned)f2bf(a6 * inv) | ((unsigned)f2bf(a7 * inv) << 16);
    *(uint4*)(aggr + (size_t)wid * 256 + cl * 8) = o;
  }
}

// ---------------- MFMA GEMM1: [N1,256] = relu([aggr1|xb] @ [W1l|W1r]^T + b1), bf16 out
__global__ __launch_bounds__(512) void mgemm1_kernel(
    const ushort* __restrict__ aggr1, const ushort* __restrict__ xb,
    const ushort* __restrict__ W1lb, const ushort* __restrict__ W1rb,
    const float* __restrict__ b1, ushort* __restrict__ h1b) {
  __shared__ ushort smem[24576];   // sA 8192 + sB 16384 ushorts = 48KB
  ushort* sA = smem;
  ushort* sB = smem + 8192;
  int t = threadIdx.x;
  int lane = t & 63;
  int w = t >> 6;
  int wm = w >> 2, wn = w & 3;
  int i0 = blockIdx.x * 128;

  int sr = t >> 3;
  int sc = (t & 7) ^ (sr & 7);
  int quad = lane >> 4;
  int l15 = lane & 15;
  int xorv = lane & 7;

  f32x4 acc[4][4];
#pragma unroll
  for (int i = 0; i < 4; ++i)
#pragma unroll
    for (int j = 0; j < 4; ++j) acc[i][j] = (f32x4)(0.f);

  for (int kt = 0; kt < 4; ++kt) {
    const ushort* Asrc = (kt < 2) ? aggr1 : xb;
    const ushort* Bsrc = (kt < 2) ? W1lb : W1rb;
    int koff = (kt & 1) * 64;
#pragma unroll
    for (int it = 0; it < 2; ++it) {
      int r = it * 64 + sr;
      gl_lds16(Asrc + (size_t)(i0 + r) * 128 + koff + sc * 8, sA + (it * 512 + t) * 8);
    }
#pragma unroll
    for (int it = 0; it < 4; ++it) {
      int r = it * 64 + sr;
      gl_lds16(Bsrc + (size_t)r * 128 + koff + sc * 8, sB + (it * 512 + t) * 8);
    }
    __syncthreads();
#pragma unroll
    for (int s = 0; s < 2; ++s) {
      int chunk = ((s * 4 + quad) ^ xorv) * 8;
      bf16x8 av[4], bv[4];
#pragma unroll
      for (int fi = 0; fi < 4; ++fi)
        av[fi] = *(const bf16x8*)(sA + (wm * 64 + fi * 16 + l15) * 64 + chunk);
#pragma unroll
      for (int fj = 0; fj < 4; ++fj)
        bv[fj] = *(const bf16x8*)(sB + (wn * 64 + fj * 16 + l15) * 64 + chunk);
#pragma unroll
      for (int fi = 0; fi < 4; ++fi)
#pragma unroll
        for (int fj = 0; fj < 4; ++fj)
          acc[fi][fj] = __builtin_amdgcn_mfma_f32_16x16x32_bf16(av[fi], bv[fj], acc[fi][fj], 0, 0, 0);
    }
    __syncthreads();
  }

  // two-phase epilogue: 4 waves at a time stage 64x64 bf16 in LDS, store uint2
  for (int ph = 0; ph < 2; ++ph) {
    if (wm == ph) {
      ushort* eb = smem + (w & 3) * 4096;
#pragma unroll
      for (int fj = 0; fj < 4; ++fj) {
        float bias = b1[wn * 64 + fj * 16 + l15];
#pragma unroll
        for (int fi = 0; fi < 4; ++fi)
#pragma unroll
          for (int r = 0; r < 4; ++r) {
            float v = fmaxf(acc[fi][fj][r] + bias, 0.f);
            eb[(fi * 16 + quad * 4 + r) * 64 + fj * 16 + l15] = f2bf(v);
          }
      }
#pragma unroll
      for (int i = 0; i < 16; ++i) {
        int row = i * 4 + (lane >> 4);
        uint2 v = *(const uint2*)(eb + row * 64 + l15 * 4);
        *(uint2*)(h1b + (size_t)(i0 + wm * 64 + row) * 256 + wn * 64 + l15 * 4) = v;
      }
    }
    __syncthreads();
  }
}

// ---------------- MFMA GEMM2 + bias + log_softmax: out[N2,64] fp32 ----------------
__global__ __launch_bounds__(256) void mgemm2_kernel(
    const ushort* __restrict__ aggr2, const ushort* __restrict__ h1b,
    const ushort* __restrict__ W2lb, const ushort* __restrict__ W2rb,
    const float* __restrict__ b2, float* __restrict__ out) {
  __shared__ ushort sA[64 * 64];
  __shared__ ushort sB[64 * 64];
  int t = threadIdx.x;
  int lane = t & 63;
  int w = t >> 6;
  int i0 = blockIdx.x * 64;

  int sr = t >> 3;
  int sc = (t & 7) ^ (sr & 7);
  int quad = lane >> 4;
  int l15 = lane & 15;
  int xorv = lane & 7;

  f32x4 acc[4];
#pragma unroll
  for (int j = 0; j < 4; ++j) acc[j] = (f32x4)(0.f);

  for (int kt = 0; kt < 8; ++kt) {
    const ushort* Asrc = (kt < 4) ? aggr2 : h1b;
    const ushort* Bsrc = (kt < 4) ? W2lb : W2rb;
    int koff = (kt & 3) * 64;
#pragma unroll
    for (int it = 0; it < 2; ++it) {
      int r = it * 32 + sr;
      gl_lds16(Asrc + (size_t)(i0 + r) * 256 + koff + sc * 8, sA + (it * 256 + t) * 8);
    }
#pragma unroll
    for (int it = 0; it < 2; ++it) {
      int r = it * 32 + sr;
      gl_lds16(Bsrc + (size_t)r * 256 + koff + sc * 8, sB + (it * 256 + t) * 8);
    }
    __syncthreads();
#pragma unroll
    for (int s = 0; s < 2; ++s) {
      int chunk = ((s * 4 + quad) ^ xorv) * 8;
      bf16x8 av = *(const bf16x8*)(sA + (w * 16 + l15) * 64 + chunk);
      bf16x8 bv[4];
#pragma unroll
      for (int fj = 0; fj < 4; ++fj)
        bv[fj] = *(const bf16x8*)(sB + (fj * 16 + l15) * 64 + chunk);
#pragma unroll
      for (int fj = 0; fj < 4; ++fj)
        acc[fj] = __builtin_amdgcn_mfma_f32_16x16x32_bf16(av, bv[fj], acc[fj], 0, 0, 0);
    }
    __syncthreads();
  }

  float b2c[4];
#pragma unroll
  for (int fj = 0; fj < 4; ++fj) b2c[fj] = b2[fj * 16 + l15];

#pragma unroll
  for (int r = 0; r < 4; ++r) {
    int row = i0 + w * 16 + quad * 4 + r;
    float v[4];
#pragma unroll
    for (int fj = 0; fj < 4; ++fj) v[fj] = acc[fj][r] + b2c[fj];
    float m = fmaxf(fmaxf(v[0], v[1]), fmaxf(v[2], v[3]));
    m = fmaxf(m, __shfl_xor(m, 1));
    m = fmaxf(m, __shfl_xor(m, 2));
    m = fmaxf(m, __shfl_xor(m, 4));
    m = fmaxf(m, __shfl_xor(m, 8));
    float ssum = __expf(v[0] - m) + __expf(v[1] - m) + __expf(v[2] - m) + __expf(v[3] - m);
    ssum += __shfl_xor(ssum, 1);
    ssum += __shfl_xor(ssum, 2);
    ssum += __shfl_xor(ssum, 4);
    ssum += __shfl_xor(ssum, 8);
    float lg = m + __logf(ssum);
#pragma unroll
    for (int fj = 0; fj < 4; ++fj)
      out[(size_t)row * 64 + fj * 16 + l15] = v[fj] - lg;
  }
}

// ---------------- launch ----------------

extern "C" void kernel_launch(void* const* d_in, const int* in_sizes, int n_in,
                              void* d_out, int out_size, void* d_ws, size_t ws_size,
                              hipStream_t stream) {
  const float* x   = (const float*)d_in[0];
  const int* src1  = (const int*)d_in[1];
  const int* dst1  = (const int*)d_in[2];
  const int* src2  = (const int*)d_in[3];
  const int* dst2  = (const int*)d_in[4];
  const float* W1l = (const float*)d_in[5];
  const float* W1r = (const float*)d_in[6];
  const float* b1  = (const float*)d_in[7];
  const float* W2l = (const float*)d_in[8];
  const float* W2r = (const float*)d_in[9];
  const float* b2  = (const float*)d_in[10];
  float* out = (float*)d_out;

  char* base = (char*)d_ws;
  ushort* xb   = (ushort*)base;                          // 67.1 MB
  ushort* ag1b = (ushort*)(base + 67108864);             // 16.8 MB
  ushort* ag2b = (ushort*)(base + 83886080);             // 8.4 MB
  unsigned* pair1 = (unsigned*)(base + 92274688);        // 8.4 MB
  unsigned* pair2 = (unsigned*)(base + 100663296);       // 8.4 MB
  ushort* h1b  = (ushort*)(base + 109051904);            // 33.6 MB
  int* cnt1  = (int*)(base + 142606336);                 // N1
  int* off1  = cnt1 + N1C;                               // N1
  int* cnt2  = off1 + N1C;                               // N2
  int* off2  = cnt2 + N2C;                               // N2
  int* btail = off2 + N2C;                               // 512
  int* ssrc1 = btail + 512;                              // E1
  int* ssrc2 = ssrc1 + E1C;                              // E2
  ushort* W1lb = (ushort*)(ssrc2 + E2C);                 // 32768
  ushort* W1rb = W1lb + 32768;
  ushort* W2lb = W1rb + 32768;
  ushort* W2rb = W2lb + 16384;

  // weights -> bf16 + btail zero (must precede mega's binA atomics)
  cvtw_kernel<<<dim3(32, 5), 256, 0, stream>>>(
      (const float4*)W1l, (const float4*)W1r, (const float4*)W2l, (const float4*)W2r,
      (ushort4*)W1lb, (ushort4*)W1rb, (ushort4*)W2lb, (ushort4*)W2rb, btail);

  // binA (320 blocks) + cvtx first half (2048 blocks), overlapping
  mega_kernel<<<2368, 256, 0, stream>>>(src1, dst1, src2, dst2, btail, pair1, pair2,
                                        (const float4*)x, (ushort4*)xb);

  // fine sort per bucket (512 blocks) + cvtx second half (2048 blocks), overlapping
  binB_kernel<<<2560, 256, 0, stream>>>(pair1, pair2, btail,
                                        off1, cnt1, ssrc1, off2, cnt2, ssrc2,
                                        (const float4*)x, (ushort4*)xb);

  // layer 1
  agg1_kernel<<<N1C / 4, 256, 0, stream>>>(xb, ssrc1, off1, cnt1, ag1b);
  mgemm1_kernel<<<N1C / 128, 512, 0, stream>>>(ag1b, xb, W1lb, W1rb, b1, h1b);

  // layer 2
  agg2_kernel<<<N2C / 4, 256, 0, stream>>>(h1b, ssrc2, off2, cnt2, ag2b);
  mgemm2_kernel<<<N2C / 64, 256, 0, stream>>>(ag2b, h1b, W2lb, W2rb, b2, out);
}

// Round 15
// 153.041 us; speedup vs baseline: 1.1915x; 1.0145x over previous
//
#include <hip/hip_runtime.h>
#include <cstdint>
#include <cstddef>

#define N0C 262144
#define N1C 65536
#define N2C 16384
#define E1C 1048576
#define E2C 262144
#define XN4 (N0C * 128 / 4)   // float4 count of x
#define XHALF (XN4 / 2)
// IN_C=128, HID_C=256, OUT_C=64
// packed pair: bits 0..17 = src (N0C=2^18), bits 18..25 = dst-local (<=255)

typedef __attribute__((ext_vector_type(8))) short bf16x8;
typedef __attribute__((ext_vector_type(4))) float f32x4;

__device__ __forceinline__ unsigned short f2bf(float f) {
  union { float f; unsigned u; } q; q.f = f;
  unsigned r = q.u + 0x7fffu + ((q.u >> 16) & 1u);
  return (unsigned short)(r >> 16);
}
__device__ __forceinline__ float blo(unsigned u) {
  union { unsigned u; float f; } q; q.u = u << 16; return q.f;
}
__device__ __forceinline__ float bhi(unsigned u) {
  union { unsigned u; float f; } q; q.u = u & 0xffff0000u; return q.f;
}
__device__ __forceinline__ void gl_lds16(const void* g, void* l) {
  __builtin_amdgcn_global_load_lds((const __attribute__((address_space(1))) void*)g,
                                   (__attribute__((address_space(3))) void*)l, 16, 0, 0);
}

__device__ __forceinline__ void cvt_range(const float4* __restrict__ x,
                                          ushort4* __restrict__ xb,
                                          int i, int stride, int end) {
  for (; i < end; i += stride) {
    float4 v = x[i];
    ushort4 o;
    o.x = f2bf(v.x); o.y = f2bf(v.y); o.z = f2bf(v.z); o.w = f2bf(v.w);
    xb[i] = o;
  }
}

// ---------------- fused weight cvt + btail zero ----------------
__global__ __launch_bounds__(256) void cvtw_kernel(
    const float4* __restrict__ W1l, const float4* __restrict__ W1r,
    const float4* __restrict__ W2l, const float4* __restrict__ W2r,
    ushort4* __restrict__ W1lb, ushort4* __restrict__ W1rb,
    ushort4* __restrict__ W2lb, ushort4* __restrict__ W2rb,
    int* __restrict__ btail) {
  int y = blockIdx.y;
  int i = blockIdx.x * 256 + threadIdx.x;
  if (y == 4) {
    if (i < 512) btail[i] = 0;
    return;
  }
  const float4* in; ushort4* outp; int n4;
  if (y == 0)      { in = W1l; outp = W1lb; n4 = 8192; }
  else if (y == 1) { in = W1r; outp = W1rb; n4 = 8192; }
  else if (y == 2) { in = W2l; outp = W2lb; n4 = 4096; }
  else             { in = W2r; outp = W2rb; n4 = 4096; }
  if (i < n4) {
    float4 v = in[i];
    ushort4 o;
    o.x = f2bf(v.x); o.y = f2bf(v.y); o.z = f2bf(v.z); o.w = f2bf(v.w);
    outp[i] = o;
  }
}

// ---------------- mega: binA (blocks 0..319) + cvtx first half (blocks 320..2367) ----
__global__ __launch_bounds__(256) void mega_kernel(
    const int* __restrict__ src1, const int* __restrict__ dst1,
    const int* __restrict__ src2, const int* __restrict__ dst2,
    int* __restrict__ btail, unsigned* __restrict__ pair1, unsigned* __restrict__ pair2,
    const float4* __restrict__ x, ushort4* __restrict__ xb) {
  __shared__ int hist[256];
  __shared__ int lofs[256];
  __shared__ int gbase[256];
  __shared__ unsigned stg[4096];
  __shared__ unsigned char bstg[4096];
  int b = blockIdx.x;
  int t = threadIdx.x;
  if (b >= 320) {
    cvt_range(x, xb, (b - 320) * 256 + t, 2048 * 256, XHALF);
    return;
  }
  const int* src; const int* dst; int shift; int dmask; int* bt; unsigned* pb; int e0;
  if (b < 256) { src = src1; dst = dst1; shift = 8; dmask = 255; bt = btail;       pb = pair1; e0 = b * 4096; }
  else         { src = src2; dst = dst2; shift = 6; dmask = 63;  bt = btail + 256; pb = pair2; e0 = (b - 256) * 4096; }
  hist[t] = 0;
  __syncthreads();
  unsigned pk[16]; int bk[16], rk[16];
#pragma unroll
  for (int k = 0; k < 16; ++k) {
    int e = e0 + k * 256 + t;
    int s = src[e];
    int d = dst[e];
    bk[k] = d >> shift;
    pk[k] = ((unsigned)(d & dmask) << 18) | (unsigned)s;
    rk[k] = atomicAdd(&hist[bk[k]], 1);
  }
  __syncthreads();
  int v = hist[t];
  lofs[t] = v;
  __syncthreads();
  for (int ofs = 1; ofs < 256; ofs <<= 1) {
    int add = (t >= ofs) ? lofs[t - ofs] : 0;
    __syncthreads();
    lofs[t] += add;
    __syncthreads();
  }
  gbase[t] = atomicAdd(&bt[t], v);
  int excl = lofs[t] - v;
  lofs[t] = excl;
  __syncthreads();
#pragma unroll
  for (int k = 0; k < 16; ++k) {
    int p = lofs[bk[k]] + rk[k];
    stg[p] = pk[k];
    bstg[p] = (unsigned char)bk[k];
  }
  __syncthreads();
  for (int i = t; i < 4096; i += 256) {
    int bki = bstg[i];
    int idx = gbase[bki] + (i - lofs[bki]);
    if (idx < 8192)
      pb[(size_t)bki * 8192 + idx] = stg[i];
  }
}

// binB: one block per BUCKET (layer1: 0..255, layer2: 256..511), packed uint pairs.
// blocks 512..2559: cvtx second half (overlaps with the bucket sort).
__global__ __launch_bounds__(256) void binB_kernel(
    const unsigned* __restrict__ pair1, const unsigned* __restrict__ pair2,
    const int* __restrict__ btail,
    int* __restrict__ off1, int* __restrict__ cnt1, int* __restrict__ ssrc1,
    int* __restrict__ off2, int* __restrict__ cnt2, int* __restrict__ ssrc2,
    const float4* __restrict__ x, ushort4* __restrict__ xb) {
  __shared__ int lcnt[256];
  __shared__ int loff[256];
  __shared__ int lcnt2[256];
  __shared__ unsigned stage[8192];
  int b = blockIdx.x;
  int t = threadIdx.x;
  if (b >= 512) {
    cvt_range(x, xb, XHALF + (b - 512) * 256 + t, 2048 * 256, XN4);
    return;
  }
  const unsigned* pb; const int* bt; int dpb; int* off; int* cnt; int* ssrc; int bl;
  if (b < 256) { bl = b;       pb = pair1 + (size_t)bl * 8192; bt = btail;       dpb = 256; off = off1; cnt = cnt1; ssrc = ssrc1; }
  else         { bl = b - 256; pb = pair2 + (size_t)bl * 8192; bt = btail + 256; dpb = 64;  off = off2; cnt = cnt2; ssrc = ssrc2; }
  lcnt[t] = (t < bl) ? bt[t] : 0;
  __syncthreads();
  for (int ofs = 128; ofs > 0; ofs >>= 1) {
    if (t < ofs) lcnt[t] += lcnt[t + ofs];
    __syncthreads();
  }
  int base = lcnt[0];
  __syncthreads();
  lcnt[t] = 0;
  lcnt2[t] = 0;
  __syncthreads();
  int n = bt[bl];
  if (n > 8192) n = 8192;
  for (int i = t; i < n; i += 256) {
    unsigned p = pb[i];
    atomicAdd(&lcnt[p >> 18], 1);
  }
  __syncthreads();
  int v = lcnt[t];
  loff[t] = v;
  __syncthreads();
  for (int ofs = 1; ofs < 256; ofs <<= 1) {
    int add = (t >= ofs) ? loff[t - ofs] : 0;
    __syncthreads();
    loff[t] += add;
    __syncthreads();
  }
  int excl = loff[t] - v;
  loff[t] = excl;
  if (t < dpb) {
    cnt[bl * dpb + t] = v;
    off[bl * dpb + t] = base + excl;
  }
  __syncthreads();
  for (int i = t; i < n; i += 256) {
    unsigned p = pb[i];
    int dl = p >> 18;
    int r = atomicAdd(&lcnt2[dl], 1);
    stage[loff[dl] + r] = p & 0x3FFFFu;
  }
  __syncthreads();
  for (int i = t; i < n; i += 256) ssrc[base + i] = (int)stage[i];
}

// ---------------- layer-1 aggregation: bf16 gather, 8 edges in flight ----------------
__global__ __launch_bounds__(256) void agg1_kernel(const ushort* __restrict__ xb,
                                                   const int* __restrict__ ssrc,
                                                   const int* __restrict__ off,
                                                   const int* __restrict__ cnt,
                                                   ushort* __restrict__ aggr) {
  int wid = (blockIdx.x * 256 + threadIdx.x) >> 6;
  int lane = threadIdx.x & 63;
  int grp = lane >> 4;
  int cl = lane & 15;
  int start = __builtin_amdgcn_readfirstlane(off[wid]);
  int n = __builtin_amdgcn_readfirstlane(cnt[wid]);
  float a0 = 0.f, a1 = 0.f, a2 = 0.f, a3 = 0.f, a4 = 0.f, a5 = 0.f, a6 = 0.f, a7 = 0.f;
  int j = 0;
  for (; j + 8 <= n; j += 8) {
    int sa = ssrc[start + j + grp];
    int sb = ssrc[start + j + 4 + grp];
    uint4 va = *(const uint4*)(xb + (size_t)sa * 128 + cl * 8);
    uint4 vb = *(const uint4*)(xb + (size_t)sb * 128 + cl * 8);
    a0 += blo(va.x) + blo(vb.x); a1 += bhi(va.x) + bhi(vb.x);
    a2 += blo(va.y) + blo(vb.y); a3 += bhi(va.y) + bhi(vb.y);
    a4 += blo(va.z) + blo(vb.z); a5 += bhi(va.z) + bhi(vb.z);
    a6 += blo(va.w) + blo(vb.w); a7 += bhi(va.w) + bhi(vb.w);
  }
  if (j + 4 <= n) {
    int s = ssrc[start + j + grp];
    uint4 v = *(const uint4*)(xb + (size_t)s * 128 + cl * 8);
    a0 += blo(v.x); a1 += bhi(v.x); a2 += blo(v.y); a3 += bhi(v.y);
    a4 += blo(v.z); a5 += bhi(v.z); a6 += blo(v.w); a7 += bhi(v.w);
    j += 4;
  }
  if (grp < n - j) {
    int s = ssrc[start + j + grp];
    uint4 v = *(const uint4*)(xb + (size_t)s * 128 + cl * 8);
    a0 += blo(v.x); a1 += bhi(v.x); a2 += blo(v.y); a3 += bhi(v.y);
    a4 += blo(v.z); a5 += bhi(v.z); a6 += blo(v.w); a7 += bhi(v.w);
  }
#define RED1(v) v += __shfl_xor(v, 16); v += __shfl_xor(v, 32);
  RED1(a0) RED1(a1) RED1(a2) RED1(a3) RED1(a4) RED1(a5) RED1(a6) RED1(a7)
#undef RED1
  if (lane < 16) {
    float inv = (n > 0) ? 1.0f / (float)n : 0.f;
    uint4 o;
    o.x = (unsigned)f2bf(a0 * inv) | ((unsigned)f2bf(a1 * inv) << 16);
    o.y = (unsigned)f2bf(a2 * inv) | ((unsigned)f2bf(a3 * inv) << 16);
    o.z = (unsigned)f2bf(a4 * inv) | ((unsigned)f2bf(a5 * inv) << 16);
    o.w = (unsigned)f2bf(a6 * inv) | ((unsigned)f2bf(a7 * inv) << 16);
    *(uint4*)(aggr + (size_t)wid * 128 + cl * 8) = o;
  }
}

// ---------------- layer-2 aggregation: bf16 gather from h1b, 8 edges in flight -------
__global__ __launch_bounds__(256) void agg2_kernel(const ushort* __restrict__ h1b,
                                                   const int* __restrict__ ssrc,
                                                   const int* __restrict__ off,
                                                   const int* __restrict__ cnt,
                                                   ushort* __restrict__ aggr) {
  int wid = (blockIdx.x * 256 + threadIdx.x) >> 6;
  int lane = threadIdx.x & 63;
  int grp = lane >> 5;
  int cl = lane & 31;
  int start = __builtin_amdgcn_readfirstlane(off[wid]);
  int n = __builtin_amdgcn_readfirstlane(cnt[wid]);
  float a0 = 0.f, a1 = 0.f, a2 = 0.f, a3 = 0.f, a4 = 0.f, a5 = 0.f, a6 = 0.f, a7 = 0.f;
  int j = 0;
  for (; j + 8 <= n; j += 8) {
    int s0 = ssrc[start + j + grp];
    int s1 = ssrc[start + j + 2 + grp];
    int s2 = ssrc[start + j + 4 + grp];
    int s3 = ssrc[start + j + 6 + grp];
    uint4 v0 = *(const uint4*)(h1b + (size_t)s0 * 256 + cl * 8);
    uint4 v1 = *(const uint4*)(h1b + (size_t)s1 * 256 + cl * 8);
    uint4 v2 = *(const uint4*)(h1b + (size_t)s2 * 256 + cl * 8);
    uint4 v3 = *(const uint4*)(h1b + (size_t)s3 * 256 + cl * 8);
    a0 += blo(v0.x) + blo(v1.x) + blo(v2.x) + blo(v3.x);
    a1 += bhi(v0.x) + bhi(v1.x) + bhi(v2.x) + bhi(v3.x);
    a2 += blo(v0.y) + blo(v1.y) + blo(v2.y) + blo(v3.y);
    a3 += bhi(v0.y) + bhi(v1.y) + bhi(v2.y) + bhi(v3.y);
    a4 += blo(v0.z) + blo(v1.z) + blo(v2.z) + blo(v3.z);
    a5 += bhi(v0.z) + bhi(v1.z) + bhi(v2.z) + bhi(v3.z);
    a6 += blo(v0.w) + blo(v1.w) + blo(v2.w) + blo(v3.w);
    a7 += bhi(v0.w) + bhi(v1.w) + bhi(v2.w) + bhi(v3.w);
  }
  for (; j + 2 <= n; j += 2) {
    int s = ssrc[start + j + grp];
    uint4 v = *(const uint4*)(h1b + (size_t)s * 256 + cl * 8);
    a0 += blo(v.x); a1 += bhi(v.x); a2 += blo(v.y); a3 += bhi(v.y);
    a4 += blo(v.z); a5 += bhi(v.z); a6 += blo(v.w); a7 += bhi(v.w);
  }
  if (grp < n - j) {
    int s = ssrc[start + j + grp];
    uint4 v = *(const uint4*)(h1b + (size_t)s * 256 + cl * 8);
    a0 += blo(v.x); a1 += bhi(v.x); a2 += blo(v.y); a3 += bhi(v.y);
    a4 += blo(v.z); a5 += bhi(v.z); a6 += blo(v.w); a7 += bhi(v.w);
  }
#define RED2(v) v += __shfl_xor(v, 32);
  RED2(a0) RED2(a1) RED2(a2) RED2(a3) RED2(a4) RED2(a5) RED2(a6) RED2(a7)
#undef RED2
  if (lane < 32) {
    float inv = (n > 0) ? 1.0f / (float)n : 0.f;
    uint4 o;
    o.x = (unsigned)f2bf(a0 * inv) | ((unsigned)f2bf(a1 * inv) << 16);
    o.y = (unsigned)f2bf(a2 * inv) | ((unsigned)f2bf(a3 * inv) << 16);
    o.z = (unsigned)f2bf(a4 * inv) | ((unsigned)f2bf(a5 * inv) << 16);
    o.w = (unsigned)f2bf(a6 * inv) | ((unsigned)f2bf(a7 * inv) << 16);
    *(uint4*)(aggr + (size_t)wid * 256 + cl * 8) = o;
  }
}

// ---------------- MFMA GEMM1: 128x128 tile, 256 threads, 4 waves (2x2), 32KB LDS ----
// grid (N1/128, 2): 1024 blocks = 4/CU for inter-block staging||MFMA overlap.
__global__ __launch_bounds__(256) void mgemm1_kernel(
    const ushort* __restrict__ aggr1, const ushort* __restrict__ xb,
    const ushort* __restrict__ W1lb, const ushort* __restrict__ W1rb,
    const float* __restrict__ b1, ushort* __restrict__ h1b) {
  __shared__ ushort smem[2 * 128 * 64];  // sA 16KB + sB 16KB
  ushort* sA = smem;
  ushort* sB = smem + 128 * 64;
  int t = threadIdx.x;
  int lane = t & 63;
  int w = t >> 6;
  int wm = w >> 1, wn = w & 1;
  int i0 = blockIdx.x * 128;
  int c0 = blockIdx.y * 128;

  int sr = t >> 3;
  int sc = (t & 7) ^ (sr & 7);
  int quad = lane >> 4;
  int l15 = lane & 15;
  int xorv = lane & 7;

  f32x4 acc[4][4];
#pragma unroll
  for (int i = 0; i < 4; ++i)
#pragma unroll
    for (int j = 0; j < 4; ++j) acc[i][j] = (f32x4)(0.f);

  for (int kt = 0; kt < 4; ++kt) {
    const ushort* Asrc = (kt < 2) ? aggr1 : xb;
    const ushort* Bsrc = (kt < 2) ? W1lb : W1rb;
    int koff = (kt & 1) * 64;
#pragma unroll
    for (int it = 0; it < 4; ++it) {
      int r = it * 32 + sr;
      gl_lds16(Asrc + (size_t)(i0 + r) * 128 + koff + sc * 8, sA + (it * 256 + t) * 8);
    }
#pragma unroll
    for (int it = 0; it < 4; ++it) {
      int r = it * 32 + sr;
      gl_lds16(Bsrc + (size_t)(c0 + r) * 128 + koff + sc * 8, sB + (it * 256 + t) * 8);
    }
    __syncthreads();
#pragma unroll
    for (int s = 0; s < 2; ++s) {
      int chunk = ((s * 4 + quad) ^ xorv) * 8;
      bf16x8 av[4], bv[4];
#pragma unroll
      for (int fi = 0; fi < 4; ++fi)
        av[fi] = *(const bf16x8*)(sA + (wm * 64 + fi * 16 + l15) * 64 + chunk);
#pragma unroll
      for (int fj = 0; fj < 4; ++fj)
        bv[fj] = *(const bf16x8*)(sB + (wn * 64 + fj * 16 + l15) * 64 + chunk);
#pragma unroll
      for (int fi = 0; fi < 4; ++fi)
#pragma unroll
        for (int fj = 0; fj < 4; ++fj)
          acc[fi][fj] = __builtin_amdgcn_mfma_f32_16x16x32_bf16(av[fi], bv[fj], acc[fi][fj], 0, 0, 0);
    }
    __syncthreads();
  }

  // epilogue: bias+relu -> bf16 via per-wave-private LDS tile, coalesced uint2 stores
  ushort* eb = smem + w * 4096;   // 64x64 ushorts per wave (4 waves = full 32KB)
#pragma unroll
  for (int fj = 0; fj < 4; ++fj) {
    float bias = b1[c0 + wn * 64 + fj * 16 + l15];
#pragma unroll
    for (int fi = 0; fi < 4; ++fi) {
#pragma unroll
      for (int r = 0; r < 4; ++r) {
        float v = fmaxf(acc[fi][fj][r] + bias, 0.f);
        eb[(fi * 16 + quad * 4 + r) * 64 + fj * 16 + l15] = f2bf(v);
      }
    }
  }
  // wave-private region: lgkmcnt ordering within wave, no barrier needed
#pragma unroll
  for (int i = 0; i < 16; ++i) {
    int row = i * 4 + (lane >> 4);
    uint2 v = *(const uint2*)(eb + row * 64 + l15 * 4);
    *(uint2*)(h1b + (size_t)(i0 + wm * 64 + row) * 256 + c0 + wn * 64 + l15 * 4) = v;
  }
}

// ---------------- MFMA GEMM2 + bias + log_softmax: out[N2,64] fp32 ----------------
__global__ __launch_bounds__(256) void mgemm2_kernel(
    const ushort* __restrict__ aggr2, const ushort* __restrict__ h1b,
    const ushort* __restrict__ W2lb, const ushort* __restrict__ W2rb,
    const float* __restrict__ b2, float* __restrict__ out) {
  __shared__ ushort sA[64 * 64];
  __shared__ ushort sB[64 * 64];
  int t = threadIdx.x;
  int lane = t & 63;
  int w = t >> 6;
  int i0 = blockIdx.x * 64;

  int sr = t >> 3;
  int sc = (t & 7) ^ (sr & 7);
  int quad = lane >> 4;
  int l15 = lane & 15;
  int xorv = lane & 7;

  f32x4 acc[4];
#pragma unroll
  for (int j = 0; j < 4; ++j) acc[j] = (f32x4)(0.f);

  for (int kt = 0; kt < 8; ++kt) {
    const ushort* Asrc = (kt < 4) ? aggr2 : h1b;
    const ushort* Bsrc = (kt < 4) ? W2lb : W2rb;
    int koff = (kt & 3) * 64;
#pragma unroll
    for (int it = 0; it < 2; ++it) {
      int r = it * 32 + sr;
      gl_lds16(Asrc + (size_t)(i0 + r) * 256 + koff + sc * 8, sA + (it * 256 + t) * 8);
    }
#pragma unroll
    for (int it = 0; it < 2; ++it) {
      int r = it * 32 + sr;
      gl_lds16(Bsrc + (size_t)r * 256 + koff + sc * 8, sB + (it * 256 + t) * 8);
    }
    __syncthreads();
#pragma unroll
    for (int s = 0; s < 2; ++s) {
      int chunk = ((s * 4 + quad) ^ xorv) * 8;
      bf16x8 av = *(const bf16x8*)(sA + (w * 16 + l15) * 64 + chunk);
      bf16x8 bv[4];
#pragma unroll
      for (int fj = 0; fj < 4; ++fj)
        bv[fj] = *(const bf16x8*)(sB + (fj * 16 + l15) * 64 + chunk);
#pragma unroll
      for (int fj = 0; fj < 4; ++fj)
        acc[fj] = __builtin_amdgcn_mfma_f32_16x16x32_bf16(av, bv[fj], acc[fj], 0, 0, 0);
    }
    __syncthreads();
  }

  float b2c[4];
#pragma unroll
  for (int fj = 0; fj < 4; ++fj) b2c[fj] = b2[fj * 16 + l15];

#pragma unroll
  for (int r = 0; r < 4; ++r) {
    int row = i0 + w * 16 + quad * 4 + r;
    float v[4];
#pragma unroll
    for (int fj = 0; fj < 4; ++fj) v[fj] = acc[fj][r] + b2c[fj];
    float m = fmaxf(fmaxf(v[0], v[1]), fmaxf(v[2], v[3]));
    m = fmaxf(m, __shfl_xor(m, 1));
    m = fmaxf(m, __shfl_xor(m, 2));
    m = fmaxf(m, __shfl_xor(m, 4));
    m = fmaxf(m, __shfl_xor(m, 8));
    float ssum = __expf(v[0] - m) + __expf(v[1] - m) + __expf(v[2] - m) + __expf(v[3] - m);
    ssum += __shfl_xor(ssum, 1);
    ssum += __shfl_xor(ssum, 2);
    ssum += __shfl_xor(ssum, 4);
    ssum += __shfl_xor(ssum, 8);
    float lg = m + __logf(ssum);
#pragma unroll
    for (int fj = 0; fj < 4; ++fj)
      out[(size_t)row * 64 + fj * 16 + l15] = v[fj] - lg;
  }
}

// ---------------- launch ----------------

extern "C" void kernel_launch(void* const* d_in, const int* in_sizes, int n_in,
                              void* d_out, int out_size, void* d_ws, size_t ws_size,
                              hipStream_t stream) {
  const float* x   = (const float*)d_in[0];
  const int* src1  = (const int*)d_in[1];
  const int* dst1  = (const int*)d_in[2];
  const int* src2  = (const int*)d_in[3];
  const int* dst2  = (const int*)d_in[4];
  const float* W1l = (const float*)d_in[5];
  const float* W1r = (const float*)d_in[6];
  const float* b1  = (const float*)d_in[7];
  const float* W2l = (const float*)d_in[8];
  const float* W2r = (const float*)d_in[9];
  const float* b2  = (const float*)d_in[10];
  float* out = (float*)d_out;

  char* base = (char*)d_ws;
  ushort* xb   = (ushort*)base;                          // 67.1 MB
  ushort* ag1b = (ushort*)(base + 67108864);             // 16.8 MB
  ushort* ag2b = (ushort*)(base + 83886080);             // 8.4 MB
  unsigned* pair1 = (unsigned*)(base + 92274688);        // 8.4 MB
  unsigned* pair2 = (unsigned*)(base + 100663296);       // 8.4 MB
  ushort* h1b  = (ushort*)(base + 109051904);            // 33.6 MB
  int* cnt1  = (int*)(base + 142606336);                 // N1
  int* off1  = cnt1 + N1C;                               // N1
  int* cnt2  = off1 + N1C;                               // N2
  int* off2  = cnt2 + N2C;                               // N2
  int* btail = off2 + N2C;                               // 512
  int* ssrc1 = btail + 512;                              // E1
  int* ssrc2 = ssrc1 + E1C;                              // E2
  ushort* W1lb = (ushort*)(ssrc2 + E2C);                 // 32768
  ushort* W1rb = W1lb + 32768;
  ushort* W2lb = W1rb + 32768;
  ushort* W2rb = W2lb + 16384;

  // weights -> bf16 + btail zero (must precede mega's binA atomics)
  cvtw_kernel<<<dim3(32, 5), 256, 0, stream>>>(
      (const float4*)W1l, (const float4*)W1r, (const float4*)W2l, (const float4*)W2r,
      (ushort4*)W1lb, (ushort4*)W1rb, (ushort4*)W2lb, (ushort4*)W2rb, btail);

  // binA (320 blocks) + cvtx first half (2048 blocks), overlapping
  mega_kernel<<<2368, 256, 0, stream>>>(src1, dst1, src2, dst2, btail, pair1, pair2,
                                        (const float4*)x, (ushort4*)xb);

  // fine sort per bucket (512 blocks) + cvtx second half (2048 blocks), overlapping
  binB_kernel<<<2560, 256, 0, stream>>>(pair1, pair2, btail,
                                        off1, cnt1, ssrc1, off2, cnt2, ssrc2,
                                        (const float4*)x, (ushort4*)xb);

  // layer 1
  agg1_kernel<<<N1C / 4, 256, 0, stream>>>(xb, ssrc1, off1, cnt1, ag1b);
  mgemm1_kernel<<<dim3(N1C / 128, 2), 256, 0, stream>>>(ag1b, xb, W1lb, W1rb, b1, h1b);

  // layer 2
  agg2_kernel<<<N2C / 4, 256, 0, stream>>>(h1b, ssrc2, off2, cnt2, ag2b);
  mgemm2_kernel<<<N2C / 64, 256, 0, stream>>>(ag2b, h1b, W2lb, W2rb, b2, out);
}